// Round 6
// baseline (689.784 us; speedup 1.0000x reference)
//
#include <hip/hip_runtime.h>
#include <hip/hip_bf16.h>

// Problem constants (from reference)
#define Nn   40000
#define Ee   640000
#define Gg   64
#define INF  128
#define Hh   256
#define OUTF 128

#define NBLK_N 157   // ceil(40000/256)

// ---------------- degree histogram ----------------
__global__ __launch_bounds__(256) void k_count(const int* __restrict__ dst, int* __restrict__ cnt) {
    int e = blockIdx.x * 256 + threadIdx.x;
    if (e < Ee) atomicAdd(&cnt[dst[e]], 1);
}

__global__ __launch_bounds__(256) void k_dis(const int* __restrict__ cnt, float* __restrict__ dis) {
    int i = blockIdx.x * 256 + threadIdx.x;
    if (i < Nn) dis[i] = rsqrtf((float)cnt[i] + 1.0f);
}

// ---------------- two-level exclusive scan: cnt[40000] -> offs[40001] ----------------
__global__ __launch_bounds__(256)
void k_scan1(const int* __restrict__ cnt, int* __restrict__ offs, int* __restrict__ partial) {
    __shared__ int sm[256];
    int i = blockIdx.x * 256 + threadIdx.x;
    int v = (i < Nn) ? cnt[i] : 0;
    sm[threadIdx.x] = v;
    __syncthreads();
#pragma unroll
    for (int d = 1; d < 256; d <<= 1) {
        int t = (threadIdx.x >= d) ? sm[threadIdx.x - d] : 0;
        __syncthreads();
        sm[threadIdx.x] += t;
        __syncthreads();
    }
    if (i < Nn) offs[i] = sm[threadIdx.x] - v;
    if (threadIdx.x == 255) partial[blockIdx.x] = sm[255];
}

__global__ __launch_bounds__(256)
void k_scan2(int* __restrict__ partial) {
    __shared__ int sm[256];
    int v = (threadIdx.x < NBLK_N) ? partial[threadIdx.x] : 0;
    sm[threadIdx.x] = v;
    __syncthreads();
#pragma unroll
    for (int d = 1; d < 256; d <<= 1) {
        int t = (threadIdx.x >= d) ? sm[threadIdx.x - d] : 0;
        __syncthreads();
        sm[threadIdx.x] += t;
        __syncthreads();
    }
    if (threadIdx.x < NBLK_N) partial[threadIdx.x] = sm[threadIdx.x] - v;
}

__global__ __launch_bounds__(256)
void k_scan3(int* __restrict__ offs, const int* __restrict__ partial) {
    int i = blockIdx.x * 256 + threadIdx.x;
    if (i < Nn) offs[i] += partial[blockIdx.x];
    if (i == 0) offs[Nn] = Ee;
}

// ---------------- CSR fill: bucket src ids by dst ----------------
__global__ __launch_bounds__(256)
void k_fill(const int* __restrict__ src, const int* __restrict__ dst,
            const int* __restrict__ offs, int* __restrict__ cursor,
            unsigned short* __restrict__ src_sorted) {
    int e = blockIdx.x * 256 + threadIdx.x;
    if (e >= Ee) return;
    int d = dst[e];
    int pos = offs[d] + atomicAdd(&cursor[d], 1);
    src_sorted[pos] = (unsigned short)src[e];
}

// ---------------- fp32 tiled GEMM + row scale: C[M,N] = (A[M,K] @ B[K,N]) * dis[row] ----------------
__global__ __launch_bounds__(256, 3)
void k_gemm128s(const float* __restrict__ A, const float* __restrict__ B,
                const float* __restrict__ dis, float* __restrict__ C,
                int M, int N, int K) {
    __shared__ float As[16][132];   // transposed A tile
    __shared__ float Bs[16][132];
    const int tid = threadIdx.x;
    const int rowBase = blockIdx.x * 128;
    const int colBase = blockIdx.y * 128;

    const int ar  = tid >> 2;            // 0..63
    const int akc = (tid & 3) * 4;       // 0,4,8,12
    const int br = tid >> 5;             // 0..7
    const int bc = (tid & 31) * 4;       // 0..124
    const int ty4 = (tid >> 4) * 4;      // 0..60
    const int tx4 = (tid & 15) * 4;      // 0..60

    float acc[8][8] = {};

    for (int k0 = 0; k0 < K; k0 += 16) {
        int r0 = rowBase + ar;       if (r0 >= M) r0 = M - 1;
        int r1 = rowBase + ar + 64;  if (r1 >= M) r1 = M - 1;
        float4 a0 = *(const float4*)&A[(size_t)r0 * K + k0 + akc];
        float4 a1 = *(const float4*)&A[(size_t)r1 * K + k0 + akc];
        float4 b0 = *(const float4*)&B[(size_t)(k0 + br) * N + colBase + bc];
        float4 b1 = *(const float4*)&B[(size_t)(k0 + br + 8) * N + colBase + bc];
        __syncthreads();
        As[akc + 0][ar] = a0.x; As[akc + 1][ar] = a0.y;
        As[akc + 2][ar] = a0.z; As[akc + 3][ar] = a0.w;
        As[akc + 0][ar + 64] = a1.x; As[akc + 1][ar + 64] = a1.y;
        As[akc + 2][ar + 64] = a1.z; As[akc + 3][ar + 64] = a1.w;
        *(float4*)&Bs[br][bc]     = b0;
        *(float4*)&Bs[br + 8][bc] = b1;
        __syncthreads();
#pragma unroll
        for (int kk = 0; kk < 16; ++kk) {
            float a[8], b[8];
            *(float4*)&a[0] = *(const float4*)&As[kk][ty4];
            *(float4*)&a[4] = *(const float4*)&As[kk][ty4 + 64];
            *(float4*)&b[0] = *(const float4*)&Bs[kk][tx4];
            *(float4*)&b[4] = *(const float4*)&Bs[kk][tx4 + 64];
#pragma unroll
            for (int i = 0; i < 8; ++i)
#pragma unroll
                for (int j = 0; j < 8; ++j)
                    acc[i][j] += a[i] * b[j];
        }
    }
#pragma unroll
    for (int i = 0; i < 8; ++i) {
        int r = rowBase + ((i < 4) ? (ty4 + i) : (ty4 + 64 + (i - 4)));
        if (r < M) {
            float s = dis[r];
            *(float4*)&C[(size_t)r * N + colBase + tx4] =
                make_float4(s * acc[i][0], s * acc[i][1], s * acc[i][2], s * acc[i][3]);
            *(float4*)&C[(size_t)r * N + colBase + tx4 + 64] =
                make_float4(s * acc[i][4], s * acc[i][5], s * acc[i][6], s * acc[i][7]);
        }
    }
}

// ---------------- sliced CSR gather v2 on pre-scaled rows h' ----------------
// One full wave per (node, 32-float slice). Lanes 0-31 handle edge i, lanes
// 32-63 handle edge i+1 (256B per load instruction = 2x128B L2-line requests).
// slice = blockIdx % SLICES: consecutive blocks land on different XCDs
// (round-robin dispatch), so XCD k only touches slice k's 5.1 MB column strip
// -> near-L2-resident (validated R4: FETCH 322->117 MB).
// Inner loop unrolled to 8 edges/iter -> ~8 independent 128B requests in
// flight per wave (R4's failure was 2 requests + 8x loop overhead).
// out[n] = dis[n]*(sum h'[src] + h'[n]) + bias (+ReLU)
template <int HH, int SLICES, bool RELU>
__global__ __launch_bounds__(256)
void k_gather4(const int* __restrict__ offs, const unsigned short* __restrict__ srcs,
               const float* __restrict__ dis, const float* __restrict__ hp,
               const float* __restrict__ bias, float* __restrict__ out) {
    const int bid = blockIdx.x;
    const int slice = bid % SLICES;
    const int chunk = bid / SLICES;
    const int n = chunk * 4 + (threadIdx.x >> 6);   // one wave per node-slice
    if (n >= Nn) return;
    const int lane = threadIdx.x & 63;
    const int half = lane >> 5;                     // which edge of the pair
    const int col = slice * 32 + (lane & 31);

    const int b = __builtin_amdgcn_readfirstlane(offs[n]);
    const int e = __builtin_amdgcn_readfirstlane(offs[n + 1]);

    float acc = 0.0f;
    int i = b;
    for (; i + 8 <= e; i += 8) {
        int s0 = srcs[i + 0 + half];
        int s1 = srcs[i + 2 + half];
        int s2 = srcs[i + 4 + half];
        int s3 = srcs[i + 6 + half];
        float v0 = hp[(size_t)s0 * HH + col];
        float v1 = hp[(size_t)s1 * HH + col];
        float v2 = hp[(size_t)s2 * HH + col];
        float v3 = hp[(size_t)s3 * HH + col];
        acc += v0 + v1 + v2 + v3;
    }
    for (; i + 2 <= e; i += 2) {
        int s0 = srcs[i + half];
        acc += hp[(size_t)s0 * HH + col];
    }
    if (i < e && half == 0) {                       // odd leftover edge
        int s0 = srcs[i];
        acc += hp[(size_t)s0 * HH + col];
    }
    // cross-half reduce: lane L += lane L+32
    acc += __shfl_down(acc, 32);
    if (half == 0) {
        float dn = dis[n];
        float r = dn * (acc + hp[(size_t)n * HH + col]) + bias[col];
        if (RELU) r = fmaxf(r, 0.0f);
        out[(size_t)n * HH + col] = r;
    }
}

// ---------------- pool phase 1: chunked segment-aware accumulation ----------------
__global__ __launch_bounds__(256)
void k_pool_accum(const float* __restrict__ emb, const int* __restrict__ batch,
                  float* __restrict__ ge_accum) {
    int n0 = blockIdx.x * 64;
    int nend = min(n0 + 64, Nn);
    int sub = threadIdx.x >> 6;
    int col = (threadIdx.x & 63) * 2;
    float ax = 0.0f, ay = 0.0f;
    int cur_g = -1;
    for (int n = n0 + sub; n < nend; n += 4) {
        int g = batch[n];
        if (g != cur_g) {
            if (cur_g >= 0) {
                unsafeAtomicAdd(&ge_accum[cur_g * OUTF + col], ax);
                unsafeAtomicAdd(&ge_accum[cur_g * OUTF + col + 1], ay);
            }
            cur_g = g; ax = 0.0f; ay = 0.0f;
        }
        float2 v = *(const float2*)&emb[(size_t)n * OUTF + col];
        ax += v.x; ay += v.y;
    }
    if (cur_g >= 0) {
        unsafeAtomicAdd(&ge_accum[cur_g * OUTF + col], ax);
        unsafeAtomicAdd(&ge_accum[cur_g * OUTF + col + 1], ay);
    }
}

// ---------------- pool phase 2: divide by segment count ----------------
__global__ __launch_bounds__(256)
void k_pool_div(const float* __restrict__ ge_accum, const int* __restrict__ batch,
                float* __restrict__ ge) {
    int idx = blockIdx.x * 256 + threadIdx.x;
    if (idx >= Gg * OUTF) return;
    int g = idx >> 7;
    int lo = 0, hi = Nn;
    while (lo < hi) { int mid = (lo + hi) >> 1; if (batch[mid] < g) lo = mid + 1; else hi = mid; }
    int start = lo;
    hi = Nn;
    while (lo < hi) { int mid = (lo + hi) >> 1; if (batch[mid] < g + 1) lo = mid + 1; else hi = mid; }
    float cnt = (float)(lo - start);
    ge[idx] = ge_accum[idx] / fmaxf(cnt, 1.0f);
}

// ---------------- logits: ge[64,128] @ W_cls[128,2] + b_cls ----------------
__global__ __launch_bounds__(128)
void k_logits(const float* __restrict__ ge, const float* __restrict__ Wc,
              const float* __restrict__ bc, float* __restrict__ out) {
    int t = threadIdx.x;
    int g = t >> 1, c = t & 1;
    float s = bc[c];
    for (int k = 0; k < 128; ++k) s += ge[g * 128 + k] * Wc[k * 2 + c];
    out[t] = s;
}

extern "C" void kernel_launch(void* const* d_in, const int* in_sizes, int n_in,
                              void* d_out, int out_size, void* d_ws, size_t ws_size,
                              hipStream_t stream) {
    const float* x     = (const float*)d_in[0];
    const int*   ei    = (const int*)d_in[1];
    const int*   batch = (const int*)d_in[2];
    const float* W_in  = (const float*)d_in[3];
    const float* b_in  = (const float*)d_in[4];
    const float* W_mid = (const float*)d_in[5];
    const float* b_mid = (const float*)d_in[6];
    const float* W_out = (const float*)d_in[7];
    const float* b_out = (const float*)d_in[8];
    const float* W_cls = (const float*)d_in[9];
    const float* b_cls = (const float*)d_in[10];

    const int* src = ei;
    const int* dst = ei + Ee;

    // workspace layout (4B units) — 83.7 MB total (proven safe)
    float* ws = (float*)d_ws;
    float* dis     = ws;                           // 0
    int*   cnt     = (int*)(ws + 40000);           // 40000
    int*   offs    = (int*)(ws + 80000);           // 80000..120064
    int*   partial = (int*)(ws + 120064);          // 192
    float* ge_accum = ws + 120256;                 // 8192
    unsigned short* src_sorted = (unsigned short*)(ws + 128448);
    float* bufA = ws + 448448;
    float* bufB = ws + 10688448;

    float* out    = (float*)d_out;
    float* ge_out = out + (size_t)Nn * OUTF;
    float* lg_out = ge_out + Gg * OUTF;

    const int nBlkE = (Ee + 255) / 256;
    const int gRows = (Nn + 127) / 128;            // 313
    const int nChunk = (Nn + 3) / 4;               // 10000 node-chunks (4 waves/block)

    // ---- CSR build ----
    hipMemsetAsync(cnt, 0, Nn * sizeof(int), stream);
    k_count<<<nBlkE, 256, 0, stream>>>(dst, cnt);
    k_dis<<<NBLK_N, 256, 0, stream>>>(cnt, dis);
    k_scan1<<<NBLK_N, 256, 0, stream>>>(cnt, offs, partial);
    k_scan2<<<1, 256, 0, stream>>>(partial);
    k_scan3<<<NBLK_N, 256, 0, stream>>>(offs, partial);
    hipMemsetAsync(cnt, 0, Nn * sizeof(int), stream);
    k_fill<<<nBlkE, 256, 0, stream>>>(src, dst, offs, cnt, src_sorted);

    // ---- layer 1 ----  bufA = dis * (x @ W_in)   (pre-scaled rows h')
    k_gemm128s<<<dim3(gRows, Hh / 128), 256, 0, stream>>>(x, W_in, dis, bufA, Nn, Hh, INF);
    k_gather4<Hh, 8, true><<<nChunk * 8, 256, 0, stream>>>(offs, src_sorted, dis, bufA, b_in, bufB);

    // ---- layer 2 ----
    k_gemm128s<<<dim3(gRows, Hh / 128), 256, 0, stream>>>(bufB, W_mid, dis, bufA, Nn, Hh, Hh);
    k_gather4<Hh, 8, true><<<nChunk * 8, 256, 0, stream>>>(offs, src_sorted, dis, bufA, b_mid, bufB);

    // ---- layer 3 -> node embeddings in d_out ----
    k_gemm128s<<<dim3(gRows, OUTF / 128), 256, 0, stream>>>(bufB, W_out, dis, bufA, Nn, OUTF, Hh);
    k_gather4<OUTF, 4, false><<<nChunk * 4, 256, 0, stream>>>(offs, src_sorted, dis, bufA, b_out, out);

    // ---- pooling + classifier ----
    hipMemsetAsync(ge_accum, 0, Gg * OUTF * sizeof(float), stream);
    k_pool_accum<<<(Nn + 63) / 64, 256, 0, stream>>>(out, batch, ge_accum);
    k_pool_div<<<(Gg * OUTF + 255) / 256, 256, 0, stream>>>(ge_accum, batch, ge_out);
    k_logits<<<1, 128, 0, stream>>>(ge_out, W_cls, b_cls, lg_out);
}

// Round 7
// 467.188 us; speedup vs baseline: 1.4765x; 1.4765x over previous
//
#include <hip/hip_runtime.h>
#include <hip/hip_bf16.h>

// Problem constants (from reference)
#define Nn   40000
#define Ee   640000
#define Gg   64
#define INF  128
#define Hh   256
#define OUTF 128

#define NBLK_N 157   // ceil(40000/256)

typedef _Float16 half4v __attribute__((ext_vector_type(4)));
typedef _Float16 half2v __attribute__((ext_vector_type(2)));

// ---------------- degree histogram ----------------
__global__ __launch_bounds__(256) void k_count(const int* __restrict__ dst, int* __restrict__ cnt) {
    int e = blockIdx.x * 256 + threadIdx.x;
    if (e < Ee) atomicAdd(&cnt[dst[e]], 1);
}

__global__ __launch_bounds__(256) void k_dis(const int* __restrict__ cnt, float* __restrict__ dis) {
    int i = blockIdx.x * 256 + threadIdx.x;
    if (i < Nn) dis[i] = rsqrtf((float)cnt[i] + 1.0f);
}

// ---------------- two-level exclusive scan: cnt[40000] -> offs[40001] ----------------
__global__ __launch_bounds__(256)
void k_scan1(const int* __restrict__ cnt, int* __restrict__ offs, int* __restrict__ partial) {
    __shared__ int sm[256];
    int i = blockIdx.x * 256 + threadIdx.x;
    int v = (i < Nn) ? cnt[i] : 0;
    sm[threadIdx.x] = v;
    __syncthreads();
#pragma unroll
    for (int d = 1; d < 256; d <<= 1) {
        int t = (threadIdx.x >= d) ? sm[threadIdx.x - d] : 0;
        __syncthreads();
        sm[threadIdx.x] += t;
        __syncthreads();
    }
    if (i < Nn) offs[i] = sm[threadIdx.x] - v;
    if (threadIdx.x == 255) partial[blockIdx.x] = sm[255];
}

__global__ __launch_bounds__(256)
void k_scan2(int* __restrict__ partial) {
    __shared__ int sm[256];
    int v = (threadIdx.x < NBLK_N) ? partial[threadIdx.x] : 0;
    sm[threadIdx.x] = v;
    __syncthreads();
#pragma unroll
    for (int d = 1; d < 256; d <<= 1) {
        int t = (threadIdx.x >= d) ? sm[threadIdx.x - d] : 0;
        __syncthreads();
        sm[threadIdx.x] += t;
        __syncthreads();
    }
    if (threadIdx.x < NBLK_N) partial[threadIdx.x] = sm[threadIdx.x] - v;
}

__global__ __launch_bounds__(256)
void k_scan3(int* __restrict__ offs, const int* __restrict__ partial) {
    int i = blockIdx.x * 256 + threadIdx.x;
    if (i < Nn) offs[i] += partial[blockIdx.x];
    if (i == 0) offs[Nn] = Ee;
}

// ---------------- CSR fill: bucket src ids by dst ----------------
__global__ __launch_bounds__(256)
void k_fill(const int* __restrict__ src, const int* __restrict__ dst,
            const int* __restrict__ offs, int* __restrict__ cursor,
            unsigned short* __restrict__ src_sorted) {
    int e = blockIdx.x * 256 + threadIdx.x;
    if (e >= Ee) return;
    int d = dst[e];
    int pos = offs[d] + atomicAdd(&cursor[d], 1);
    src_sorted[pos] = (unsigned short)src[e];
}

// ---------------- fp32 tiled GEMM, fp16 scaled output: C16 = (half)(dis[row] * (A@B)) ----------------
// 128x128 tile, 256 threads, 8x8 micro-tile as 4 quadrants of 4x4, BK=16.
__global__ __launch_bounds__(256, 3)
void k_gemm128h(const float* __restrict__ A, const float* __restrict__ B,
                const float* __restrict__ dis, _Float16* __restrict__ C16,
                int M, int N, int K) {
    __shared__ float As[16][132];   // transposed A tile
    __shared__ float Bs[16][132];
    const int tid = threadIdx.x;
    const int rowBase = blockIdx.x * 128;
    const int colBase = blockIdx.y * 128;

    const int ar  = tid >> 2;            // 0..63
    const int akc = (tid & 3) * 4;       // 0,4,8,12
    const int br = tid >> 5;             // 0..7
    const int bc = (tid & 31) * 4;       // 0..124
    const int ty4 = (tid >> 4) * 4;      // 0..60
    const int tx4 = (tid & 15) * 4;      // 0..60

    float acc[8][8] = {};

    for (int k0 = 0; k0 < K; k0 += 16) {
        int r0 = rowBase + ar;       if (r0 >= M) r0 = M - 1;
        int r1 = rowBase + ar + 64;  if (r1 >= M) r1 = M - 1;
        float4 a0 = *(const float4*)&A[(size_t)r0 * K + k0 + akc];
        float4 a1 = *(const float4*)&A[(size_t)r1 * K + k0 + akc];
        float4 b0 = *(const float4*)&B[(size_t)(k0 + br) * N + colBase + bc];
        float4 b1 = *(const float4*)&B[(size_t)(k0 + br + 8) * N + colBase + bc];
        __syncthreads();
        As[akc + 0][ar] = a0.x; As[akc + 1][ar] = a0.y;
        As[akc + 2][ar] = a0.z; As[akc + 3][ar] = a0.w;
        As[akc + 0][ar + 64] = a1.x; As[akc + 1][ar + 64] = a1.y;
        As[akc + 2][ar + 64] = a1.z; As[akc + 3][ar + 64] = a1.w;
        *(float4*)&Bs[br][bc]     = b0;
        *(float4*)&Bs[br + 8][bc] = b1;
        __syncthreads();
#pragma unroll
        for (int kk = 0; kk < 16; ++kk) {
            float a[8], b[8];
            *(float4*)&a[0] = *(const float4*)&As[kk][ty4];
            *(float4*)&a[4] = *(const float4*)&As[kk][ty4 + 64];
            *(float4*)&b[0] = *(const float4*)&Bs[kk][tx4];
            *(float4*)&b[4] = *(const float4*)&Bs[kk][tx4 + 64];
#pragma unroll
            for (int i = 0; i < 8; ++i)
#pragma unroll
                for (int j = 0; j < 8; ++j)
                    acc[i][j] += a[i] * b[j];
        }
    }
#pragma unroll
    for (int i = 0; i < 8; ++i) {
        int r = rowBase + ((i < 4) ? (ty4 + i) : (ty4 + 64 + (i - 4)));
        if (r < M) {
            float s = dis[r];
            half4v h0 = { (_Float16)(s * acc[i][0]), (_Float16)(s * acc[i][1]),
                          (_Float16)(s * acc[i][2]), (_Float16)(s * acc[i][3]) };
            half4v h1 = { (_Float16)(s * acc[i][4]), (_Float16)(s * acc[i][5]),
                          (_Float16)(s * acc[i][6]), (_Float16)(s * acc[i][7]) };
            *(half4v*)&C16[(size_t)r * N + colBase + tx4]      = h0;
            *(half4v*)&C16[(size_t)r * N + colBase + tx4 + 64] = h1;
        }
    }
}

// ---------------- CSR gather on fp16 pre-scaled rows h' = dis*h ----------------
// out[n] = dis[n] * ( sum_{src} h'[src] + h'[n] ) + bias (+ReLU), fp32 accumulate.
// One wave per node, V halves per lane (V=4: one 512B row per wave-instruction).
// Unsliced: R4/R6 showed slicing trades HBM fetch for MORE line requests; the
// binding resource is ~53G line-requests/s, so fp16 (half the lines) is the lever.
template <int HH, bool RELU>
__global__ __launch_bounds__(256)
void k_gatherh(const int* __restrict__ offs, const unsigned short* __restrict__ srcs,
               const float* __restrict__ dis, const _Float16* __restrict__ hp,
               const float* __restrict__ bias, float* __restrict__ out) {
    constexpr int V = HH / 64;   // 4 (H=256) or 2 (H=128)
    typedef _Float16 halfv __attribute__((ext_vector_type(V)));
    int n = blockIdx.x * 4 + (threadIdx.x >> 6);
    if (n >= Nn) return;
    int lane = threadIdx.x & 63;
    int col = lane * V;
    int b = __builtin_amdgcn_readfirstlane(offs[n]);
    int e = __builtin_amdgcn_readfirstlane(offs[n + 1]);

    float acc[V];
    {
        halfv sv = *(const halfv*)(hp + (size_t)n * HH + col);   // self row h'[n]
#pragma unroll
        for (int j = 0; j < V; ++j) acc[j] = (float)sv[j];
    }

    int i = b;
    for (; i + 4 <= e; i += 4) {
        int s0 = srcs[i], s1 = srcs[i + 1], s2 = srcs[i + 2], s3 = srcs[i + 3];
        halfv v0 = *(const halfv*)(hp + (size_t)s0 * HH + col);
        halfv v1 = *(const halfv*)(hp + (size_t)s1 * HH + col);
        halfv v2 = *(const halfv*)(hp + (size_t)s2 * HH + col);
        halfv v3 = *(const halfv*)(hp + (size_t)s3 * HH + col);
#pragma unroll
        for (int j = 0; j < V; ++j)
            acc[j] += (float)v0[j] + (float)v1[j] + (float)v2[j] + (float)v3[j];
    }
    for (; i < e; ++i) {
        int s0 = srcs[i];
        halfv v0 = *(const halfv*)(hp + (size_t)s0 * HH + col);
#pragma unroll
        for (int j = 0; j < V; ++j) acc[j] += (float)v0[j];
    }

    float dn = dis[n];
    float* op = out + (size_t)n * HH + col;
    if constexpr (V == 4) {
        float4 bv = *(const float4*)&bias[col];
        float4 r;
        r.x = dn * acc[0] + bv.x;
        r.y = dn * acc[1] + bv.y;
        r.z = dn * acc[2] + bv.z;
        r.w = dn * acc[3] + bv.w;
        if (RELU) {
            r.x = fmaxf(r.x, 0.0f); r.y = fmaxf(r.y, 0.0f);
            r.z = fmaxf(r.z, 0.0f); r.w = fmaxf(r.w, 0.0f);
        }
        *(float4*)op = r;
    } else {
        float2 bv = *(const float2*)&bias[col];
        float2 r;
        r.x = dn * acc[0] + bv.x;
        r.y = dn * acc[1] + bv.y;
        if (RELU) { r.x = fmaxf(r.x, 0.0f); r.y = fmaxf(r.y, 0.0f); }
        *(float2*)op = r;
    }
}

// ---------------- pool phase 1: chunked segment-aware accumulation ----------------
__global__ __launch_bounds__(256)
void k_pool_accum(const float* __restrict__ emb, const int* __restrict__ batch,
                  float* __restrict__ ge_accum) {
    int n0 = blockIdx.x * 64;
    int nend = min(n0 + 64, Nn);
    int sub = threadIdx.x >> 6;
    int col = (threadIdx.x & 63) * 2;
    float ax = 0.0f, ay = 0.0f;
    int cur_g = -1;
    for (int n = n0 + sub; n < nend; n += 4) {
        int g = batch[n];
        if (g != cur_g) {
            if (cur_g >= 0) {
                unsafeAtomicAdd(&ge_accum[cur_g * OUTF + col], ax);
                unsafeAtomicAdd(&ge_accum[cur_g * OUTF + col + 1], ay);
            }
            cur_g = g; ax = 0.0f; ay = 0.0f;
        }
        float2 v = *(const float2*)&emb[(size_t)n * OUTF + col];
        ax += v.x; ay += v.y;
    }
    if (cur_g >= 0) {
        unsafeAtomicAdd(&ge_accum[cur_g * OUTF + col], ax);
        unsafeAtomicAdd(&ge_accum[cur_g * OUTF + col + 1], ay);
    }
}

// ---------------- pool phase 2: divide by segment count ----------------
__global__ __launch_bounds__(256)
void k_pool_div(const float* __restrict__ ge_accum, const int* __restrict__ batch,
                float* __restrict__ ge) {
    int idx = blockIdx.x * 256 + threadIdx.x;
    if (idx >= Gg * OUTF) return;
    int g = idx >> 7;
    int lo = 0, hi = Nn;
    while (lo < hi) { int mid = (lo + hi) >> 1; if (batch[mid] < g) lo = mid + 1; else hi = mid; }
    int start = lo;
    hi = Nn;
    while (lo < hi) { int mid = (lo + hi) >> 1; if (batch[mid] < g + 1) lo = mid + 1; else hi = mid; }
    float cnt = (float)(lo - start);
    ge[idx] = ge_accum[idx] / fmaxf(cnt, 1.0f);
}

// ---------------- logits: ge[64,128] @ W_cls[128,2] + b_cls ----------------
__global__ __launch_bounds__(128)
void k_logits(const float* __restrict__ ge, const float* __restrict__ Wc,
              const float* __restrict__ bc, float* __restrict__ out) {
    int t = threadIdx.x;
    int g = t >> 1, c = t & 1;
    float s = bc[c];
    for (int k = 0; k < 128; ++k) s += ge[g * 128 + k] * Wc[k * 2 + c];
    out[t] = s;
}

extern "C" void kernel_launch(void* const* d_in, const int* in_sizes, int n_in,
                              void* d_out, int out_size, void* d_ws, size_t ws_size,
                              hipStream_t stream) {
    const float* x     = (const float*)d_in[0];
    const int*   ei    = (const int*)d_in[1];
    const int*   batch = (const int*)d_in[2];
    const float* W_in  = (const float*)d_in[3];
    const float* b_in  = (const float*)d_in[4];
    const float* W_mid = (const float*)d_in[5];
    const float* b_mid = (const float*)d_in[6];
    const float* W_out = (const float*)d_in[7];
    const float* b_out = (const float*)d_in[8];
    const float* W_cls = (const float*)d_in[9];
    const float* b_cls = (const float*)d_in[10];

    const int* src = ei;
    const int* dst = ei + Ee;

    // workspace layout (4B units) — same proven 83.7 MB envelope
    float* ws = (float*)d_ws;
    float* dis     = ws;                           // 0
    int*   cnt     = (int*)(ws + 40000);           // 40000
    int*   offs    = (int*)(ws + 80000);           // 80000..120064
    int*   partial = (int*)(ws + 120064);          // 192
    float* ge_accum = ws + 120256;                 // 8192
    unsigned short* src_sorted = (unsigned short*)(ws + 128448);
    _Float16* hA = (_Float16*)(ws + 448448);       // fp16 h' staging: 40000*256*2B = 20.5 MB
    float* bufB = ws + 10688448;                   // fp32 gather output, 41 MB

    float* out    = (float*)d_out;
    float* ge_out = out + (size_t)Nn * OUTF;
    float* lg_out = ge_out + Gg * OUTF;

    const int nBlkE = (Ee + 255) / 256;
    const int gRows = (Nn + 127) / 128;            // 313
    const int nBlkG = (Nn + 3) / 4;                // 10000

    // ---- CSR build ----
    hipMemsetAsync(cnt, 0, Nn * sizeof(int), stream);
    k_count<<<nBlkE, 256, 0, stream>>>(dst, cnt);
    k_dis<<<NBLK_N, 256, 0, stream>>>(cnt, dis);
    k_scan1<<<NBLK_N, 256, 0, stream>>>(cnt, offs, partial);
    k_scan2<<<1, 256, 0, stream>>>(partial);
    k_scan3<<<NBLK_N, 256, 0, stream>>>(offs, partial);
    hipMemsetAsync(cnt, 0, Nn * sizeof(int), stream);
    k_fill<<<nBlkE, 256, 0, stream>>>(src, dst, offs, cnt, src_sorted);

    // ---- layer 1 ----  hA = (fp16) dis * (x @ W_in)
    k_gemm128h<<<dim3(gRows, Hh / 128), 256, 0, stream>>>(x, W_in, dis, hA, Nn, Hh, INF);
    k_gatherh<Hh, true><<<nBlkG, 256, 0, stream>>>(offs, src_sorted, dis, hA, b_in, bufB);

    // ---- layer 2 ----
    k_gemm128h<<<dim3(gRows, Hh / 128), 256, 0, stream>>>(bufB, W_mid, dis, hA, Nn, Hh, Hh);
    k_gatherh<Hh, true><<<nBlkG, 256, 0, stream>>>(offs, src_sorted, dis, hA, b_mid, bufB);

    // ---- layer 3 -> node embeddings in d_out ----
    k_gemm128h<<<dim3(gRows, OUTF / 128), 256, 0, stream>>>(bufB, W_out, dis, hA, Nn, OUTF, Hh);
    k_gatherh<OUTF, false><<<nBlkG, 256, 0, stream>>>(offs, src_sorted, dis, hA, b_out, out);

    // ---- pooling + classifier ----
    hipMemsetAsync(ge_accum, 0, Gg * OUTF * sizeof(float), stream);
    k_pool_accum<<<(Nn + 63) / 64, 256, 0, stream>>>(out, batch, ge_accum);
    k_pool_div<<<(Gg * OUTF + 255) / 256, 256, 0, stream>>>(ge_accum, batch, ge_out);
    k_logits<<<1, 128, 0, stream>>>(ge_out, W_cls, b_cls, lg_out);
}

// Round 8
// 361.804 us; speedup vs baseline: 1.9065x; 1.2913x over previous
//
#include <hip/hip_runtime.h>
#include <hip/hip_bf16.h>

// Problem constants (from reference)
#define Nn   40000
#define Ee   640000
#define Gg   64
#define INF  128
#define Hh   256
#define OUTF 128

#define NBLK_N 157   // ceil(40000/256)

typedef _Float16 half8 __attribute__((ext_vector_type(8)));
typedef float    f32x4 __attribute__((ext_vector_type(4)));

// ---------------- degree histogram ----------------
__global__ __launch_bounds__(256) void k_count(const int* __restrict__ dst, int* __restrict__ cnt) {
    int e = blockIdx.x * 256 + threadIdx.x;
    if (e < Ee) atomicAdd(&cnt[dst[e]], 1);
}

__global__ __launch_bounds__(256) void k_dis(const int* __restrict__ cnt, float* __restrict__ dis) {
    int i = blockIdx.x * 256 + threadIdx.x;
    if (i < Nn) dis[i] = rsqrtf((float)cnt[i] + 1.0f);
}

// ---------------- two-level exclusive scan: cnt[40000] -> offs[40001] ----------------
__global__ __launch_bounds__(256)
void k_scan1(const int* __restrict__ cnt, int* __restrict__ offs, int* __restrict__ partial) {
    __shared__ int sm[256];
    int i = blockIdx.x * 256 + threadIdx.x;
    int v = (i < Nn) ? cnt[i] : 0;
    sm[threadIdx.x] = v;
    __syncthreads();
#pragma unroll
    for (int d = 1; d < 256; d <<= 1) {
        int t = (threadIdx.x >= d) ? sm[threadIdx.x - d] : 0;
        __syncthreads();
        sm[threadIdx.x] += t;
        __syncthreads();
    }
    if (i < Nn) offs[i] = sm[threadIdx.x] - v;
    if (threadIdx.x == 255) partial[blockIdx.x] = sm[255];
}

__global__ __launch_bounds__(256)
void k_scan2(int* __restrict__ partial) {
    __shared__ int sm[256];
    int v = (threadIdx.x < NBLK_N) ? partial[threadIdx.x] : 0;
    sm[threadIdx.x] = v;
    __syncthreads();
#pragma unroll
    for (int d = 1; d < 256; d <<= 1) {
        int t = (threadIdx.x >= d) ? sm[threadIdx.x - d] : 0;
        __syncthreads();
        sm[threadIdx.x] += t;
        __syncthreads();
    }
    if (threadIdx.x < NBLK_N) partial[threadIdx.x] = sm[threadIdx.x] - v;
}

__global__ __launch_bounds__(256)
void k_scan3(int* __restrict__ offs, const int* __restrict__ partial) {
    int i = blockIdx.x * 256 + threadIdx.x;
    if (i < Nn) offs[i] += partial[blockIdx.x];
    if (i == 0) offs[Nn] = Ee;
}

// ---------------- CSR fill: bucket src ids by dst ----------------
__global__ __launch_bounds__(256)
void k_fill(const int* __restrict__ src, const int* __restrict__ dst,
            const int* __restrict__ offs, int* __restrict__ cursor,
            unsigned short* __restrict__ src_sorted) {
    int e = blockIdx.x * 256 + threadIdx.x;
    if (e >= Ee) return;
    int d = dst[e];
    int pos = offs[d] + atomicAdd(&cursor[d], 1);
    src_sorted[pos] = (unsigned short)src[e];
}

// ---------------- conversions ----------------
// x fp32 -> fp16, vectorized (Nn*INF = 5.12M elems, %4==0)
__global__ __launch_bounds__(256)
void k_cvt_x(const float* __restrict__ x, _Float16* __restrict__ xh) {
    int i = (blockIdx.x * 256 + threadIdx.x) * 4;
    if (i >= Nn * INF) return;
    float4 v = *(const float4*)&x[i];
    xh[i + 0] = (_Float16)v.x;
    xh[i + 1] = (_Float16)v.y;
    xh[i + 2] = (_Float16)v.z;
    xh[i + 3] = (_Float16)v.w;
}

// W[K][N] fp32 -> Wt[N][K] fp16 (tiny matrices; uncoalesced reads OK)
__global__ __launch_bounds__(256)
void k_cvt_wt(const float* __restrict__ W, _Float16* __restrict__ Wt, int K, int N) {
    int idx = blockIdx.x * 256 + threadIdx.x;
    if (idx >= K * N) return;
    int n = idx / K;
    int k = idx - n * K;
    Wt[idx] = (_Float16)W[(size_t)k * N + n];
}

// ---------------- fp16 MFMA GEMM: C16[M,N] = (half)(dis[row] * (A @ Wt^T)) ----------------
// A[M,K] fp16 row-major; Wt[N,K] fp16 (weights pre-transposed, K contiguous).
// 128x128 tile, 4 waves (2x2), each wave 64x64 = 4x4 tiles of 16x16, BK=32.
// mfma_f32_16x16x32_f16: A-frag A[m=lane&15][k=quad*8+j]; B-frag Wt[n=lane&15][k=quad*8+j];
// C/D: col=lane&15, row=quad*4+reg (HW-verified mapping, dtype-independent).
// LDS rows padded to 40 halves (80 B, 16B-aligned; frag reads 2-way banks = free).
__global__ __launch_bounds__(256)
void k_gemm_mfma(const _Float16* __restrict__ A, const _Float16* __restrict__ Wt,
                 const float* __restrict__ dis, _Float16* __restrict__ C16,
                 int M, int N, int K) {
    __shared__ _Float16 Alds[128 * 40];
    __shared__ _Float16 Blds[128 * 40];
    const int tid = threadIdx.x;
    const int lane = tid & 63;
    const int waveId = tid >> 6;
    const int waveRow = waveId >> 1;          // 0..1
    const int waveCol = waveId & 1;           // 0..1
    const int quad = lane >> 4;               // 0..3
    const int m16 = lane & 15;
    const int rowBase = blockIdx.x * 128;
    const int colBase = blockIdx.y * 128;

    // staging: thread t loads 32B of one (row, k0) strip; 2 threads per row
    const int sRow  = tid >> 1;               // 0..127
    const int sKoff = (tid & 1) * 16;         // 0 or 16 halves

    int gr = rowBase + sRow; if (gr >= M) gr = M - 1;
    const int gn = colBase + sRow;            // N is multiple of 128, no guard

    f32x4 acc[4][4];
#pragma unroll
    for (int i = 0; i < 4; ++i)
#pragma unroll
        for (int j = 0; j < 4; ++j)
            acc[i][j] = (f32x4){0.0f, 0.0f, 0.0f, 0.0f};

    for (int k0 = 0; k0 < K; k0 += 32) {
        const uint4* ap = (const uint4*)(A  + (size_t)gr * K + k0 + sKoff);
        const uint4* bp = (const uint4*)(Wt + (size_t)gn * K + k0 + sKoff);
        uint4 a0 = ap[0], a1 = ap[1];
        uint4 b0 = bp[0], b1 = bp[1];
        __syncthreads();
        *(uint4*)&Alds[sRow * 40 + sKoff]     = a0;
        *(uint4*)&Alds[sRow * 40 + sKoff + 8] = a1;
        *(uint4*)&Blds[sRow * 40 + sKoff]     = b0;
        *(uint4*)&Blds[sRow * 40 + sKoff + 8] = b1;
        __syncthreads();

        half8 a_frag[4], b_frag[4];
#pragma unroll
        for (int rt = 0; rt < 4; ++rt)
            a_frag[rt] = *(const half8*)&Alds[(waveRow * 64 + rt * 16 + m16) * 40 + quad * 8];
#pragma unroll
        for (int ct = 0; ct < 4; ++ct)
            b_frag[ct] = *(const half8*)&Blds[(waveCol * 64 + ct * 16 + m16) * 40 + quad * 8];
#pragma unroll
        for (int rt = 0; rt < 4; ++rt)
#pragma unroll
            for (int ct = 0; ct < 4; ++ct)
                acc[rt][ct] = __builtin_amdgcn_mfma_f32_16x16x32_f16(
                    a_frag[rt], b_frag[ct], acc[rt][ct], 0, 0, 0);
    }

    // epilogue: scale by dis[row], cast fp16, scalar stores
#pragma unroll
    for (int rt = 0; rt < 4; ++rt) {
        const int rb = rowBase + waveRow * 64 + rt * 16 + quad * 4;
#pragma unroll
        for (int r = 0; r < 4; ++r) {
            const int row = rb + r;
            if (row < M) {
                const float s = dis[row];
#pragma unroll
                for (int ct = 0; ct < 4; ++ct) {
                    const int col = colBase + waveCol * 64 + ct * 16 + m16;
                    C16[(size_t)row * N + col] = (_Float16)(s * acc[rt][ct][r]);
                }
            }
        }
    }
}

// ---------------- CSR gather on fp16 pre-scaled rows h' = dis*h ----------------
// out[n] = dis[n]*(sum h'[src] + h'[n]) + bias (+ReLU), fp32 accumulate.
// H16OUT: write fp16 activation (next GEMM's A); else fp32 (final embeddings).
template <int HH, bool RELU, bool H16OUT>
__global__ __launch_bounds__(256)
void k_gatherh(const int* __restrict__ offs, const unsigned short* __restrict__ srcs,
               const float* __restrict__ dis, const _Float16* __restrict__ hp,
               const float* __restrict__ bias, void* __restrict__ outv) {
    constexpr int V = HH / 64;   // 4 (H=256) or 2 (H=128)
    typedef _Float16 halfv __attribute__((ext_vector_type(V)));
    int n = blockIdx.x * 4 + (threadIdx.x >> 6);
    if (n >= Nn) return;
    int lane = threadIdx.x & 63;
    int col = lane * V;
    int b = __builtin_amdgcn_readfirstlane(offs[n]);
    int e = __builtin_amdgcn_readfirstlane(offs[n + 1]);

    float acc[V];
    {
        halfv sv = *(const halfv*)(hp + (size_t)n * HH + col);   // self row h'[n]
#pragma unroll
        for (int j = 0; j < V; ++j) acc[j] = (float)sv[j];
    }

    int i = b;
    for (; i + 4 <= e; i += 4) {
        int s0 = srcs[i], s1 = srcs[i + 1], s2 = srcs[i + 2], s3 = srcs[i + 3];
        halfv v0 = *(const halfv*)(hp + (size_t)s0 * HH + col);
        halfv v1 = *(const halfv*)(hp + (size_t)s1 * HH + col);
        halfv v2 = *(const halfv*)(hp + (size_t)s2 * HH + col);
        halfv v3 = *(const halfv*)(hp + (size_t)s3 * HH + col);
#pragma unroll
        for (int j = 0; j < V; ++j)
            acc[j] += (float)v0[j] + (float)v1[j] + (float)v2[j] + (float)v3[j];
    }
    for (; i < e; ++i) {
        int s0 = srcs[i];
        halfv v0 = *(const halfv*)(hp + (size_t)s0 * HH + col);
#pragma unroll
        for (int j = 0; j < V; ++j) acc[j] += (float)v0[j];
    }

    float dn = dis[n];
    float r[V];
#pragma unroll
    for (int j = 0; j < V; ++j) {
        r[j] = dn * acc[j] + bias[col + j];
        if (RELU) r[j] = fmaxf(r[j], 0.0f);
    }
    if constexpr (H16OUT) {
        halfv hv;
#pragma unroll
        for (int j = 0; j < V; ++j) hv[j] = (_Float16)r[j];
        *(halfv*)((_Float16*)outv + (size_t)n * HH + col) = hv;
    } else {
        if constexpr (V == 4) {
            *(float4*)((float*)outv + (size_t)n * HH + col) = make_float4(r[0], r[1], r[2], r[3]);
        } else {
            *(float2*)((float*)outv + (size_t)n * HH + col) = make_float2(r[0], r[1]);
        }
    }
}

// ---------------- pool phase 1: chunked segment-aware accumulation ----------------
__global__ __launch_bounds__(256)
void k_pool_accum(const float* __restrict__ emb, const int* __restrict__ batch,
                  float* __restrict__ ge_accum) {
    int n0 = blockIdx.x * 64;
    int nend = min(n0 + 64, Nn);
    int sub = threadIdx.x >> 6;
    int col = (threadIdx.x & 63) * 2;
    float ax = 0.0f, ay = 0.0f;
    int cur_g = -1;
    for (int n = n0 + sub; n < nend; n += 4) {
        int g = batch[n];
        if (g != cur_g) {
            if (cur_g >= 0) {
                unsafeAtomicAdd(&ge_accum[cur_g * OUTF + col], ax);
                unsafeAtomicAdd(&ge_accum[cur_g * OUTF + col + 1], ay);
            }
            cur_g = g; ax = 0.0f; ay = 0.0f;
        }
        float2 v = *(const float2*)&emb[(size_t)n * OUTF + col];
        ax += v.x; ay += v.y;
    }
    if (cur_g >= 0) {
        unsafeAtomicAdd(&ge_accum[cur_g * OUTF + col], ax);
        unsafeAtomicAdd(&ge_accum[cur_g * OUTF + col + 1], ay);
    }
}

// ---------------- pool phase 2: divide by segment count ----------------
__global__ __launch_bounds__(256)
void k_pool_div(const float* __restrict__ ge_accum, const int* __restrict__ batch,
                float* __restrict__ ge) {
    int idx = blockIdx.x * 256 + threadIdx.x;
    if (idx >= Gg * OUTF) return;
    int g = idx >> 7;
    int lo = 0, hi = Nn;
    while (lo < hi) { int mid = (lo + hi) >> 1; if (batch[mid] < g) lo = mid + 1; else hi = mid; }
    int start = lo;
    hi = Nn;
    while (lo < hi) { int mid = (lo + hi) >> 1; if (batch[mid] < g + 1) lo = mid + 1; else hi = mid; }
    float cnt = (float)(lo - start);
    ge[idx] = ge_accum[idx] / fmaxf(cnt, 1.0f);
}

// ---------------- logits: ge[64,128] @ W_cls[128,2] + b_cls ----------------
__global__ __launch_bounds__(128)
void k_logits(const float* __restrict__ ge, const float* __restrict__ Wc,
              const float* __restrict__ bc, float* __restrict__ out) {
    int t = threadIdx.x;
    int g = t >> 1, c = t & 1;
    float s = bc[c];
    for (int k = 0; k < 128; ++k) s += ge[g * 128 + k] * Wc[k * 2 + c];
    out[t] = s;
}

extern "C" void kernel_launch(void* const* d_in, const int* in_sizes, int n_in,
                              void* d_out, int out_size, void* d_ws, size_t ws_size,
                              hipStream_t stream) {
    const float* x     = (const float*)d_in[0];
    const int*   ei    = (const int*)d_in[1];
    const int*   batch = (const int*)d_in[2];
    const float* W_in  = (const float*)d_in[3];
    const float* b_in  = (const float*)d_in[4];
    const float* W_mid = (const float*)d_in[5];
    const float* b_mid = (const float*)d_in[6];
    const float* W_out = (const float*)d_in[7];
    const float* b_out = (const float*)d_in[8];
    const float* W_cls = (const float*)d_in[9];
    const float* b_cls = (const float*)d_in[10];

    const int* src = ei;
    const int* dst = ei + Ee;

    // workspace layout (4B units), total ~53 MB (< proven 83.7 MB envelope)
    float* ws = (float*)d_ws;
    float* dis      = ws;                          // 40000
    int*   cnt      = (int*)(ws + 40000);          // 40000
    int*   offs     = (int*)(ws + 80000);          // 40064
    int*   partial  = (int*)(ws + 120064);         // 192
    float* ge_accum = ws + 120256;                 // 8192
    unsigned short* src_sorted = (unsigned short*)(ws + 128448);   // 640000 ushort = 320000 fl
    _Float16* xh     = (_Float16*)(ws + 448448);   // 40000*128 h = 2,560,000 fl
    _Float16* Wt_in  = (_Float16*)(ws + 3008448);  // 256*128 h = 16384 fl
    _Float16* Wt_mid = (_Float16*)(ws + 3024832);  // 256*256 h = 32768 fl
    _Float16* Wt_out = (_Float16*)(ws + 3057600);  // 128*256 h = 16384 fl
    _Float16* hA     = (_Float16*)(ws + 3073984);  // 40000*256 h = 5,120,000 fl
    _Float16* actA   = (_Float16*)(ws + 8193984);  // 40000*256 h = 5,120,000 fl
    // end = 13,313,984 floats = 53.3 MB

    float* out    = (float*)d_out;
    float* ge_out = out + (size_t)Nn * OUTF;
    float* lg_out = ge_out + Gg * OUTF;

    const int nBlkE = (Ee + 255) / 256;
    const int gRows = (Nn + 127) / 128;            // 313
    const int nBlkG = (Nn + 3) / 4;                // 10000

    // ---- CSR build ----
    hipMemsetAsync(cnt, 0, Nn * sizeof(int), stream);
    k_count<<<nBlkE, 256, 0, stream>>>(dst, cnt);
    k_dis<<<NBLK_N, 256, 0, stream>>>(cnt, dis);
    k_scan1<<<NBLK_N, 256, 0, stream>>>(cnt, offs, partial);
    k_scan2<<<1, 256, 0, stream>>>(partial);
    k_scan3<<<NBLK_N, 256, 0, stream>>>(offs, partial);
    hipMemsetAsync(cnt, 0, Nn * sizeof(int), stream);
    k_fill<<<nBlkE, 256, 0, stream>>>(src, dst, offs, cnt, src_sorted);

    // ---- fp16 conversions ----
    k_cvt_x<<<(Nn * INF / 4 + 255) / 256, 256, 0, stream>>>(x, xh);
    k_cvt_wt<<<(INF * Hh + 255) / 256, 256, 0, stream>>>(W_in, Wt_in, INF, Hh);
    k_cvt_wt<<<(Hh * Hh + 255) / 256, 256, 0, stream>>>(W_mid, Wt_mid, Hh, Hh);
    k_cvt_wt<<<(Hh * OUTF + 255) / 256, 256, 0, stream>>>(W_out, Wt_out, Hh, OUTF);

    // ---- layer 1 ----  hA = (fp16) dis * (x @ W_in)
    k_gemm_mfma<<<dim3(gRows, Hh / 128), 256, 0, stream>>>(xh, Wt_in, dis, hA, Nn, Hh, INF);
    k_gatherh<Hh, true, true><<<nBlkG, 256, 0, stream>>>(offs, src_sorted, dis, hA, b_in, actA);

    // ---- layer 2 ----
    k_gemm_mfma<<<dim3(gRows, Hh / 128), 256, 0, stream>>>(actA, Wt_mid, dis, hA, Nn, Hh, Hh);
    k_gatherh<Hh, true, true><<<nBlkG, 256, 0, stream>>>(offs, src_sorted, dis, hA, b_mid, actA);

    // ---- layer 3 -> node embeddings (fp32) in d_out ----
    k_gemm_mfma<<<dim3(gRows, OUTF / 128), 256, 0, stream>>>(actA, Wt_out, dis, hA, Nn, OUTF, Hh);
    k_gatherh<OUTF, false, false><<<nBlkG, 256, 0, stream>>>(offs, src_sorted, dis, hA, b_out, out);

    // ---- pooling + classifier ----
    hipMemsetAsync(ge_accum, 0, Gg * OUTF * sizeof(float), stream);
    k_pool_accum<<<(Nn + 63) / 64, 256, 0, stream>>>(out, batch, ge_accum);
    k_pool_div<<<(Gg * OUTF + 255) / 256, 256, 0, stream>>>(ge_accum, batch, ge_out);
    k_logits<<<1, 128, 0, stream>>>(ge_out, W_cls, b_cls, lg_out);
}